// Round 5
// baseline (145.901 us; speedup 1.0000x reference)
//
#include <hip/hip_runtime.h>

constexpr int Bn = 8, S = 2048, E = 1024, H = 64;
// E^-0.5 * log2(e) folded into q: scores come out of QK^T already in log2
// domain, so softmax is exp2f(s - m) with no per-element LOG2E multiply.
constexpr float SCALE = 0.03125f * 1.44269504f;

typedef __attribute__((ext_vector_type(8))) short short8;  // 8 bf16
typedef __attribute__((ext_vector_type(4))) float f32x4;   // MFMA C/D

__device__ __forceinline__ unsigned short f2bf(float f) {
  unsigned u = __builtin_bit_cast(unsigned, f);
  u += 0x7fffu + ((u >> 16) & 1u);    // RNE
  return (unsigned short)(u >> 16);
}
__device__ __forceinline__ ushort4 f4bf(float4 f) {
  return make_ushort4(f2bf(f.x), f2bf(f.y), f2bf(f.z), f2bf(f.w));
}

// ---------- W [1024][64] fp32 -> WT3 [3][64][1024] bf16 ----------
__global__ __launch_bounds__(256) void wtrans_kernel(
    const float* __restrict__ Wq, const float* __restrict__ Wk,
    const float* __restrict__ Wv, unsigned short* __restrict__ WT3) {
  __shared__ unsigned short tb[64][72];
  const int m = blockIdx.x >> 4;
  const int e0 = (blockIdx.x & 15) * 64;
  const float* W = (m == 0) ? Wq : (m == 1) ? Wk : Wv;
  const int t = threadIdx.x;
#pragma unroll
  for (int it = 0; it < 4; ++it) {
    int idx = t + it * 256;
    int r = idx >> 4, c4 = idx & 15;
    float4 f = ((const float4*)(W + (long)(e0 + r) * H))[c4];
    *(ushort4*)&tb[r][c4 * 4] = f4bf(f);
  }
  __syncthreads();
#pragma unroll
  for (int it = 0; it < 4; ++it) {
    int idx = t + it * 256;
    int h = idx >> 4, e4 = idx & 15;
    ushort4 u = make_ushort4(tb[e4 * 4 + 0][h], tb[e4 * 4 + 1][h],
                             tb[e4 * 4 + 2][h], tb[e4 * 4 + 3][h]);
    ((ushort4*)(WT3 + (long)(m * 64 + h) * E + e0))[e4] = u;
  }
}

// ---------- QKV GEMM, m97-style: M=32 x N=192, BK=128, LDS-dense ----------
__global__ __launch_bounds__(256) void qkv_kernel(
    const float* __restrict__ x, const unsigned short* __restrict__ WT3,
    unsigned short* __restrict__ q, unsigned short* __restrict__ kk,
    unsigned short* __restrict__ vT) {
  __shared__ unsigned short xs[32][136];    // [seq-row][e in chunk]
  __shared__ unsigned short ws[192][136];   // [out-col j][e in chunk]
  const int t = threadIdx.x;
  const int w = t >> 6, lane = t & 63, l15 = lane & 15, g = lane >> 4;
  const long row0 = (long)blockIdx.x * 32;
  const int xrow = t >> 5, xslot = t & 31;  // x: 8 rows x 32 float4 / iter
  const int wrow = t >> 4, wslot = t & 15;  // W: 16 rows x 16 short8 / iter

  f32x4 acc[2][3];
#pragma unroll
  for (int rt = 0; rt < 2; ++rt)
#pragma unroll
    for (int ct = 0; ct < 3; ++ct) acc[rt][ct] = f32x4{0.f, 0.f, 0.f, 0.f};

  float4 px[4];
  short8 pw[12];
  // prologue: chunk 0 -> regs -> LDS
#pragma unroll
  for (int it = 0; it < 4; ++it)
    px[it] = ((const float4*)(x + (row0 + xrow + it * 8) * E))[xslot];
#pragma unroll
  for (int it = 0; it < 12; ++it)
    pw[it] = *(const short8*)(WT3 + (long)(wrow + it * 16) * E + wslot * 8);
#pragma unroll
  for (int it = 0; it < 4; ++it)
    *(ushort4*)&xs[xrow + it * 8][xslot * 4] = f4bf(px[it]);
#pragma unroll
  for (int it = 0; it < 12; ++it)
    *(short8*)&ws[wrow + it * 16][wslot * 8] = pw[it];

  for (int c = 0; c < 8; ++c) {             // 8 chunks of 128 e
    __syncthreads();                        // staged chunk visible
    if (c < 7) {                            // dense prefetch of chunk c+1
      const int e0 = (c + 1) * 128;
#pragma unroll
      for (int it = 0; it < 4; ++it)
        px[it] = ((const float4*)(x + (row0 + xrow + it * 8) * E + e0))[xslot];
#pragma unroll
      for (int it = 0; it < 12; ++it)
        pw[it] = *(const short8*)(WT3 + (long)(wrow + it * 16) * E + e0 + wslot * 8);
    }
#pragma unroll
    for (int kh = 0; kh < 4; ++kh) {
      short8 a0 = *(const short8*)&xs[l15][kh * 32 + g * 8];
      short8 a1 = *(const short8*)&xs[16 + l15][kh * 32 + g * 8];
#pragma unroll
      for (int ct = 0; ct < 3; ++ct) {
        short8 b = *(const short8*)&ws[w * 48 + ct * 16 + l15][kh * 32 + g * 8];
        acc[0][ct] = __builtin_amdgcn_mfma_f32_16x16x32_bf16(a0, b, acc[0][ct], 0, 0, 0);
        acc[1][ct] = __builtin_amdgcn_mfma_f32_16x16x32_bf16(a1, b, acc[1][ct], 0, 0, 0);
      }
    }
    __syncthreads();                        // LDS reads done
    if (c < 7) {
#pragma unroll
      for (int it = 0; it < 4; ++it)
        *(ushort4*)&xs[xrow + it * 8][xslot * 4] = f4bf(px[it]);
#pragma unroll
      for (int it = 0; it < 12; ++it)
        *(short8*)&ws[wrow + it * 16][wslot * 8] = pw[it];
    }
  }

  const int bb = (int)(row0 >> 11);
  const int srow = (int)(row0 & 2047);
#pragma unroll
  for (int ct = 0; ct < 3; ++ct) {
    const int col = w * 48 + ct * 16 + l15;
    const int mm = col >> 6, ch = col & 63;
#pragma unroll
    for (int rt = 0; rt < 2; ++rt) {
      const int srl = rt * 16 + g * 4;
      if (mm == 0) {
#pragma unroll
        for (int r = 0; r < 4; ++r)
          q[(row0 + srl + r) * H + ch] = f2bf(acc[rt][ct][r] * SCALE);
      } else if (mm == 1) {
#pragma unroll
        for (int r = 0; r < 4; ++r)
          kk[(row0 + srl + r) * H + ch] = f2bf(acc[rt][ct][r]);
      } else {
        ushort4 v4 = make_ushort4(f2bf(acc[rt][ct][0]), f2bf(acc[rt][ct][1]),
                                  f2bf(acc[rt][ct][2]), f2bf(acc[rt][ct][3]));
        *(ushort4*)(vT + ((long)bb * H + ch) * S + srow + srl) = v4;
      }
    }
  }
}

// ---------- causal flash attention: 1 q-tile (16 rows) per block ---------
// r4 post-mortem: spill fixed (total 153->144), attn ~38-40us, still
// latency-bound (r2 evidence: Occ ~20-27%, VALUBusy 16%, MfmaUtil 3%).
// This round attacks the exposed per-pass serial chain two ways:
//  (a) occupancy 2->3 blocks/CU via __launch_bounds__(256,3): VGPR cap 170
//      >= ~160 live (r3's failure was cap 128 < need). 12 waves/CU.
//  (b) defer-max (T13): scores are log2-domain; skip the 2 dependent
//      ds_bpermute max-shuffles + O-rescale unless some lane's tile-max
//      exceeds m_+10 (P bounded by 2^10, exact algebra preserved; m_ is
//      only a reference point). After pass 1 the fast path is ~always hit
//      -> ~300 cyc off a ~1000 cyc chain.
// Structure: block = 256 thr / 4 waves owns ONE 16-row q-tile, waves split
// K64 tiles stride-4, in-block 4-way LDS merge; grid 1024 longest-first.
__global__ __launch_bounds__(256, 3) void attn_kernel(
    const unsigned short* __restrict__ q, const unsigned short* __restrict__ k,
    const unsigned short* __restrict__ vT, float* __restrict__ out) {
  __shared__ unsigned short pl[4][16][72];  // per-wave P^T [qrow][key]
  __shared__ float Om[4][64][17];           // partial O^T [wave][h][qrow]
  __shared__ float ms[4][16], ls[4][16];
  const int t = threadIdx.x;
  const int w = t >> 6, lane = t & 63, l15 = lane & 15, g = lane >> 4;
  const int b = blockIdx.x & 7, p = blockIdx.x >> 3;
  const int qt = 127 - p;                   // longest blocks dispatch first
  const int qrow0 = qt * 16;
  const int nt = (qt >> 2) + 1;             // K64 tiles covering keys<=rows
  const unsigned short* kb = k + (long)b * S * H;
  const unsigned short* vb = vT + (long)b * H * S;

  const unsigned short* qp = q + ((long)b * S + qrow0 + l15) * H + g * 8;
  short8 bq0 = *(const short8*)qp;          // Q B-frags: n=l15=qrow, k=h
  short8 bq1 = *(const short8*)(qp + 32);

  f32x4 O[4];
#pragma unroll
  for (int c = 0; c < 4; ++c) O[c] = f32x4{0.f, 0.f, 0.f, 0.f};
  float m_ = -1e30f, l_ = 0.f;              // l_ is per-lane partial

  short8 ak[4][2];
  int kt = w;                               // wave w: tiles kt == w (mod 4)
  if (kt < nt) {                            // prologue K frags
#pragma unroll
    for (int c = 0; c < 4; ++c)
#pragma unroll
      for (int kh = 0; kh < 2; ++kh)
        ak[c][kh] = *(const short8*)(kb + (long)(kt * 64 + c * 16 + l15) * H + kh * 32 + g * 8);
  }

  for (; kt < nt; kt += 4) {
    // V^T A-frags issued early (consumed at the end of the iteration)
    short8 av[4][2];
#pragma unroll
    for (int c = 0; c < 4; ++c)
#pragma unroll
      for (int kh = 0; kh < 2; ++kh)
        av[c][kh] = *(const short8*)(vb + (long)(c * 16 + l15) * S + kt * 64 + kh * 32 + g * 8);
    // ---- S^T = K Q^T : D[m=key][n=qrow], already in log2 units ----
    f32x4 sc[4];
#pragma unroll
    for (int c = 0; c < 4; ++c) {
      sc[c] = f32x4{0.f, 0.f, 0.f, 0.f};
      sc[c] = __builtin_amdgcn_mfma_f32_16x16x32_bf16(ak[c][0], bq0, sc[c], 0, 0, 0);
      sc[c] = __builtin_amdgcn_mfma_f32_16x16x32_bf16(ak[c][1], bq1, sc[c], 0, 0, 0);
    }
    // prefetch K frags for kt+4
    if (kt + 4 < nt) {
#pragma unroll
      for (int c = 0; c < 4; ++c)
#pragma unroll
        for (int kh = 0; kh < 2; ++kh)
          ak[c][kh] = *(const short8*)(kb + (long)((kt + 4) * 64 + c * 16 + l15) * H + kh * 32 + g * 8);
    }
    if (kt == nt - 1) {                     // diagonal tile: mask key > qrow
#pragma unroll
      for (int c = 0; c < 4; ++c)
#pragma unroll
        for (int r = 0; r < 4; ++r)
          if (kt * 64 + c * 16 + g * 4 + r > qrow0 + l15) sc[c][r] = -1e30f;
    }
    // ---- per-lane tree max ----
    float x0 = fmaxf(fmaxf(sc[0][0], sc[0][1]), fmaxf(sc[0][2], sc[0][3]));
    float x1 = fmaxf(fmaxf(sc[1][0], sc[1][1]), fmaxf(sc[1][2], sc[1][3]));
    float x2 = fmaxf(fmaxf(sc[2][0], sc[2][1]), fmaxf(sc[2][2], sc[2][3]));
    float x3 = fmaxf(fmaxf(sc[3][0], sc[3][1]), fmaxf(sc[3][2], sc[3][3]));
    float pmax = fmaxf(fmaxf(x0, x1), fmaxf(x2, x3));
    // ---- defer-max (T13): slow path only when some lane grows past THR --
    if (!__all(pmax - m_ <= 10.0f)) {
      float mx = fmaxf(pmax, __shfl_xor(pmax, 16));
      mx = fmaxf(mx, __shfl_xor(mx, 32));
      float mn = fmaxf(m_, mx);             // uniform across the 4 g-groups
      float al = exp2f(m_ - mn);
      l_ *= al;
#pragma unroll
      for (int c = 0; c < 4; ++c)
#pragma unroll
        for (int r = 0; r < 4; ++r) O[c][r] *= al;
      m_ = mn;
    }
#pragma unroll
    for (int c = 0; c < 4; ++c)
#pragma unroll
      for (int r = 0; r < 4; ++r) sc[c][r] = exp2f(sc[c][r] - m_);
    float s0 = (sc[0][0] + sc[0][1]) + (sc[0][2] + sc[0][3]);
    float s1 = (sc[1][0] + sc[1][1]) + (sc[1][2] + sc[1][3]);
    float s2 = (sc[2][0] + sc[2][1]) + (sc[2][2] + sc[2][3]);
    float s3 = (sc[3][0] + sc[3][1]) + (sc[3][2] + sc[3][3]);
    l_ += (s0 + s1) + (s2 + s3);            // per-lane partial; no shuffles
    // ---- P^T -> per-wave LDS ----
#pragma unroll
    for (int c = 0; c < 4; ++c) {
      ushort4 p4 = make_ushort4(f2bf(sc[c][0]), f2bf(sc[c][1]),
                                f2bf(sc[c][2]), f2bf(sc[c][3]));
      *(ushort4*)&pl[w][l15][c * 16 + g * 4] = p4;
    }
    // ---- O^T += V^T P^T ----
    short8 bp0 = *(const short8*)&pl[w][l15][g * 8];
    short8 bp1 = *(const short8*)&pl[w][l15][32 + g * 8];
#pragma unroll
    for (int c = 0; c < 4; ++c) {
      O[c] = __builtin_amdgcn_mfma_f32_16x16x32_bf16(av[c][0], bp0, O[c], 0, 0, 0);
      O[c] = __builtin_amdgcn_mfma_f32_16x16x32_bf16(av[c][1], bp1, O[c], 0, 0, 0);
    }
  }

  // complete the deferred l reduction (sum partials across the 4 g-groups)
  l_ += __shfl_xor(l_, 16);
  l_ += __shfl_xor(l_, 32);

  // ---- 4-way in-block merge ----
  if (g == 0) { ms[w][l15] = m_; ls[w][l15] = l_; }
#pragma unroll
  for (int c = 0; c < 4; ++c)
#pragma unroll
    for (int r = 0; r < 4; ++r)
      Om[w][c * 16 + g * 4 + r][l15] = O[c][r];
  __syncthreads();
  {
    const int row = t >> 4, h0 = (t & 15) * 4;   // 256 thr = 16 rows x 16 h-quads
    float m0 = ms[0][row], m1 = ms[1][row], m2 = ms[2][row], m3 = ms[3][row];
    float mstar = fmaxf(fmaxf(m0, m1), fmaxf(m2, m3));
    float f0 = exp2f(m0 - mstar), f1 = exp2f(m1 - mstar);
    float f2 = exp2f(m2 - mstar), f3 = exp2f(m3 - mstar);
    float inv = 1.0f / (ls[0][row] * f0 + ls[1][row] * f1 +
                        ls[2][row] * f2 + ls[3][row] * f3);
    float4 o;
    o.x = (Om[0][h0 + 0][row] * f0 + Om[1][h0 + 0][row] * f1 +
           Om[2][h0 + 0][row] * f2 + Om[3][h0 + 0][row] * f3) * inv;
    o.y = (Om[0][h0 + 1][row] * f0 + Om[1][h0 + 1][row] * f1 +
           Om[2][h0 + 1][row] * f2 + Om[3][h0 + 1][row] * f3) * inv;
    o.z = (Om[0][h0 + 2][row] * f0 + Om[1][h0 + 2][row] * f1 +
           Om[2][h0 + 2][row] * f2 + Om[3][h0 + 2][row] * f3) * inv;
    o.w = (Om[0][h0 + 3][row] * f0 + Om[1][h0 + 3][row] * f1 +
           Om[2][h0 + 3][row] * f2 + Om[3][h0 + 3][row] * f3) * inv;
    *(float4*)(out + ((long)b * S + qrow0 + row) * H + h0) = o;
  }
}

extern "C" void kernel_launch(void* const* d_in, const int* in_sizes, int n_in,
                              void* d_out, int out_size, void* d_ws, size_t ws_size,
                              hipStream_t stream) {
  const float* x  = (const float*)d_in[0];
  const float* Wq = (const float*)d_in[1];
  const float* Wk = (const float*)d_in[2];
  const float* Wv = (const float*)d_in[3];
  float* outp = (float*)d_out;
  unsigned short* WT3 = (unsigned short*)d_ws;                       // 384 KB
  unsigned short* q  = (unsigned short*)((char*)d_ws + 512 * 1024);  // 2 MB each
  unsigned short* kk = q + (size_t)Bn * S * H;
  unsigned short* vT = kk + (size_t)Bn * S * H;
  wtrans_kernel<<<dim3(48), dim3(256), 0, stream>>>(Wq, Wk, Wv, WT3);
  qkv_kernel<<<dim3((Bn * S) / 32), dim3(256), 0, stream>>>(x, WT3, q, kk, vT);
  attn_kernel<<<dim3(Bn * 128), dim3(256), 0, stream>>>(q, kk, vT, outp);
}